// Round 5
// baseline (1144.282 us; speedup 1.0000x reference)
//
#include <hip/hip_runtime.h>

#define LL 12
#define NN 2048
#define KK 8
#define SS 4
#define HH 256
#define LN (LL*NN)
#define VV 50000

typedef __bf16 bf16_t;
typedef __bf16 bf16x8 __attribute__((ext_vector_type(8)));
typedef __bf16 bf16x4v __attribute__((ext_vector_type(4)));
typedef float f32x4 __attribute__((ext_vector_type(4)));

__device__ __forceinline__ float sigmoidf_(float x) { return 1.f / (1.f + expf(-x)); }

// ---------------- E f32 -> bf16 ----------------
__global__ __launch_bounds__(256) void k_cvtE(const float* __restrict__ src,
                                              bf16_t* __restrict__ dst, int n4)
{
    int i = blockIdx.x * 256 + threadIdx.x;
    const int stride = gridDim.x * 256;
    for (; i < n4; i += stride) {
        const float4 v = ((const float4*)src)[i];
        bf16x4v o;
        o[0] = (bf16_t)v.x; o[1] = (bf16_t)v.y; o[2] = (bf16_t)v.z; o[3] = (bf16_t)v.w;
        ((bf16x4v*)dst)[i] = o;
    }
}

// ---------------- weight transposes (f32 (K,N) -> bf16 (N,K)) ----------------
__global__ __launch_bounds__(256) void k_cvtW(
    const float* __restrict__ linW, const float* __restrict__ WW,
    const float* __restrict__ UfW, const float* __restrict__ UiW,
    bf16_t* __restrict__ linWt, bf16_t* __restrict__ WWt,
    bf16_t* __restrict__ UfWt, bf16_t* __restrict__ UiWt)
{
    int i = blockIdx.x * 256 + threadIdx.x;      // total 786432
    if (i < 262144) {                            // linW (1024,256) -> (256,1024)
        const int rr = i >> 8, cc = i & 255;
        linWt[(size_t)cc * 1024 + rr] = (bf16_t)linW[i];
        return;
    }
    i -= 262144;
    if (i < 262144) {                            // WW (256,1024) -> (1024,256)
        const int rr = i >> 10, cc = i & 1023;
        WWt[(size_t)cc * 256 + rr] = (bf16_t)WW[i];
        return;
    }
    i -= 262144;
    if (i < 65536) {                             // UfW (256,256) -> (256,256)
        const int rr = i >> 8, cc = i & 255;
        UfWt[(size_t)cc * 256 + rr] = (bf16_t)UfW[i];
        return;
    }
    i -= 65536;
    if (i < 196608) {                            // UiW (256,768) -> (768,256)
        const int rr = i / 768, cc = i - rr * 768;
        UiWt[(size_t)cc * 256 + rr] = (bf16_t)UiW[i];
    }
}

// ---------------- embed GEMM: x = concat_s(Ebf[tok_s]) @ lin_W + lin_b ----------------
// 768 blocks x 512 thr (8 waves, 2x4); block tile 64x256, wave tile 32x64; A prefetch.
__global__ __launch_bounds__(512) void k_embed(
    const int* __restrict__ tok1, const int* __restrict__ tok2,
    const bf16_t* __restrict__ Ebf, const bf16_t* __restrict__ linWt,
    const float* __restrict__ linb, bf16_t* __restrict__ xout)
{
    __shared__ int toff[64][SS];
    const int t = threadIdx.x;
    const int m0 = blockIdx.x * 64;
    if (t < 256) {
        const int lr = t >> 2, s = t & 3;
        const int m = m0 + lr;
        const int e = (m >= LN) ? 1 : 0;
        const int rrow = m - e * LN;
        const int* tok = e ? tok2 : tok1;
        toff[lr][s] = tok[(size_t)rrow * SS + s] * HH;
    }
    __syncthreads();
    const int lane = t & 63, w = t >> 6;
    const int wm = w >> 2, wn = w & 3;
    const int r = lane & 15, kg = lane >> 4;
    const int lr0 = wm * 32 + r, lr1 = lr0 + 16;
    const bf16_t* bp[4];
    #pragma unroll
    for (int j = 0; j < 4; ++j)
        bp[j] = linWt + (size_t)(wn * 64 + j * 16 + r) * 1024 + kg * 8;

    const f32x4 zero = {0.f, 0.f, 0.f, 0.f};
    f32x4 acc[2][4];
    #pragma unroll
    for (int mi = 0; mi < 2; ++mi)
        #pragma unroll
        for (int j = 0; j < 4; ++j) acc[mi][j] = zero;

    const int koff = kg * 8;
    bf16x8 a0c = *(const bf16x8*)(Ebf + (size_t)toff[lr0][0] + koff);
    bf16x8 a1c = *(const bf16x8*)(Ebf + (size_t)toff[lr1][0] + koff);
    for (int k0 = 0; k0 < 1024; k0 += 32) {
        bf16x8 a0n = a0c, a1n = a1c;
        const int k1 = k0 + 32;
        if (k1 < 1024) {
            const int s = k1 >> 8, off = (k1 & 255) + koff;
            a0n = *(const bf16x8*)(Ebf + (size_t)toff[lr0][s] + off);
            a1n = *(const bf16x8*)(Ebf + (size_t)toff[lr1][s] + off);
        }
        #pragma unroll
        for (int j = 0; j < 4; ++j) {
            const bf16x8 b = *(const bf16x8*)bp[j];
            acc[0][j] = __builtin_amdgcn_mfma_f32_16x16x32_bf16(a0c, b, acc[0][j], 0, 0, 0);
            acc[1][j] = __builtin_amdgcn_mfma_f32_16x16x32_bf16(a1c, b, acc[1][j], 0, 0, 0);
            bp[j] += 32;
        }
        a0c = a0n; a1c = a1n;
    }
    const int crow = m0 + wm * 32 + kg * 4;
    #pragma unroll
    for (int j = 0; j < 4; ++j) {
        const int ccol = wn * 64 + j * 16 + r;
        const float bv = linb[ccol];
        #pragma unroll
        for (int mi = 0; mi < 2; ++mi)
            #pragma unroll
            for (int jj = 0; jj < 4; ++jj)
                xout[(size_t)(crow + mi * 16 + jj) * HH + ccol] =
                    (bf16_t)(acc[mi][j][jj] + bv);
    }
}

// ---------------- fully fused scan step: one kernel per step ----------------
// 256 blocks x 512 thr (8 waves), 16 rows/block. All intermediates in LDS.
// Hf computed REDUNDANTLY for this block's 128 gathered child rows (in-place in chH).
__global__ __launch_bounds__(512) void k_stepF(
    const bf16_t* __restrict__ xbf, const bf16_t* __restrict__ hprev,
    const float* __restrict__ cprev,
    const int* __restrict__ idx1, const int* __restrict__ idx2, const int l,
    const bf16_t* __restrict__ UfWt, const float* __restrict__ Ufb,
    const bf16_t* __restrict__ UiWt, const float* __restrict__ Uib,
    const bf16_t* __restrict__ WWt, const float* __restrict__ Wb,
    bf16_t* __restrict__ hnext, float* __restrict__ cnext)
{
    __shared__ __align__(16) bf16_t chH[128 * 256];    // 64 KB: child h, becomes Hf
    __shared__ __align__(16) bf16_t hsumL[16 * 256];   // 8 KB
    __shared__ __align__(16) bf16_t WxL[16 * 1024];    // 32 KB
    __shared__ __align__(16) bf16_t iuoL[16 * 768];    // 24 KB
    __shared__ int childL[16][KK];

    const int t = threadIdx.x;
    const int g0 = blockIdx.x * 16;
    const int e  = g0 >> 11;                 // block-uniform (16 | 2048)
    const int n0 = g0 & (NN - 1);
    const int* idxp = (e ? idx2 : idx1) + ((size_t)l * NN + n0) * KK;

    // ---- phase 0: child ids + gather child h rows into chH (swizzled slices) ----
    {
        const int j = t >> 2, qq = t & 3;    // slot j = rr*8+k; 4 threads per slot
        const int rr = j >> 3, k = j & 7;
        const int il = idxp[rr * KK + k];
        const int ch = (il >= 1) ? (e * NN + il - 1) : -1;
        if (qq == 0) childL[rr][k] = ch;
        const bf16_t* src = hprev + (size_t)ch * HH;
        #pragma unroll
        for (int i = 0; i < 8; ++i) {
            const int s = qq + 4 * i;        // logical 16B slice 0..31
            bf16x8 v;
            for (int jj = 0; jj < 8; ++jj) v[jj] = (bf16_t)0.f;
            if (ch >= 0) v = *(const bf16x8*)(src + s * 8);
            const int ps = (s + 4 * (j & 7)) & 31;
            *(bf16x8*)(chH + (size_t)j * 256 + ps * 8) = v;
        }
    }
    __syncthreads();

    // ---- phase 1: hsum rows (f32 accumulate over 8 children) ----
    {
        const int rr = t >> 5, c8 = t & 31;
        float acc[8] = {0.f, 0.f, 0.f, 0.f, 0.f, 0.f, 0.f, 0.f};
        #pragma unroll
        for (int k = 0; k < KK; ++k) {
            const int ps = (c8 + 4 * k) & 31;                  // (slot&7)==k
            const bf16x8 v = *(const bf16x8*)(chH + (size_t)(rr * 8 + k) * 256 + ps * 8);
            #pragma unroll
            for (int jj = 0; jj < 8; ++jj) acc[jj] += (float)v[jj];
        }
        bf16x8 o;
        #pragma unroll
        for (int jj = 0; jj < 8; ++jj) o[jj] = (bf16_t)acc[jj];
        const int ps = (c8 + 4 * (rr & 7)) & 31;
        *(bf16x8*)(hsumL + (size_t)rr * 256 + ps * 8) = o;
    }
    __syncthreads();

    const int lane = t & 63, w = t >> 6;
    const int r = lane & 15, kg = lane >> 4;
    const f32x4 zero = {0.f, 0.f, 0.f, 0.f};

    // ---- GEMM 1: Hf = chH @ UfW + Ufb, in place (each wave owns rows 16w..16w+15) ----
    {
        const int row = 16 * w + r;
        const bf16_t* bp[16];
        #pragma unroll
        for (int n = 0; n < 16; ++n)
            bp[n] = UfWt + (size_t)(n * 16 + r) * 256 + kg * 8;
        f32x4 acc[16];
        #pragma unroll
        for (int n = 0; n < 16; ++n) acc[n] = zero;
        for (int k0 = 0; k0 < 256; k0 += 32) {
            const int ps = (((k0 >> 3) + kg) + 4 * (row & 7)) & 31;
            const bf16x8 a = *(const bf16x8*)(chH + (size_t)row * 256 + ps * 8);
            #pragma unroll
            for (int n = 0; n < 16; ++n) {
                const bf16x8 b = *(const bf16x8*)bp[n];
                acc[n] = __builtin_amdgcn_mfma_f32_16x16x32_bf16(a, b, acc[n], 0, 0, 0);
                bp[n] += 32;
            }
        }
        __syncthreads();   // all waves done reading chH before in-place overwrite
        #pragma unroll
        for (int n = 0; n < 16; ++n) {
            const int col = n * 16 + r;
            const float bv = Ufb[col];
            #pragma unroll
            for (int jj = 0; jj < 4; ++jj) {
                const int slot = 16 * w + kg * 4 + jj;
                const int ps = ((col >> 3) + 4 * (slot & 7)) & 31;
                chH[(size_t)slot * 256 + ps * 8 + (col & 7)] = (bf16_t)(acc[n][jj] + bv);
            }
        }
    }

    // ---- GEMM 2: Wx = x_l @ WW + Wb (wave w -> n-tiles 8w..8w+7 of 64) ----
    {
        const bf16_t* ap = xbf + ((size_t)e * LN + (size_t)l * NN + n0 + r) * HH + kg * 8;
        const bf16_t* bp[8];
        #pragma unroll
        for (int j = 0; j < 8; ++j)
            bp[j] = WWt + (size_t)((8 * w + j) * 16 + r) * 256 + kg * 8;
        f32x4 acc[8];
        #pragma unroll
        for (int j = 0; j < 8; ++j) acc[j] = zero;
        for (int k0 = 0; k0 < 256; k0 += 32) {
            const bf16x8 a = *(const bf16x8*)(ap + k0);
            #pragma unroll
            for (int j = 0; j < 8; ++j) {
                const bf16x8 b = *(const bf16x8*)bp[j];
                acc[j] = __builtin_amdgcn_mfma_f32_16x16x32_bf16(a, b, acc[j], 0, 0, 0);
                bp[j] += 32;
            }
        }
        #pragma unroll
        for (int j = 0; j < 8; ++j) {
            const int col = (8 * w + j) * 16 + r;
            const float bv = Wb[col];
            #pragma unroll
            for (int jj = 0; jj < 4; ++jj)
                WxL[(size_t)(kg * 4 + jj) * 1024 + col] = (bf16_t)(acc[j][jj] + bv);
        }
    }

    // ---- GEMM 3: iuo = hsum @ UiW + Uib (wave w -> n-tiles 6w..6w+5 of 48) ----
    {
        const bf16_t* bp[6];
        #pragma unroll
        for (int j = 0; j < 6; ++j)
            bp[j] = UiWt + (size_t)((6 * w + j) * 16 + r) * 256 + kg * 8;
        f32x4 acc[6];
        #pragma unroll
        for (int j = 0; j < 6; ++j) acc[j] = zero;
        for (int k0 = 0; k0 < 256; k0 += 32) {
            const int ps = (((k0 >> 3) + kg) + 4 * (r & 7)) & 31;
            const bf16x8 a = *(const bf16x8*)(hsumL + (size_t)r * 256 + ps * 8);
            #pragma unroll
            for (int j = 0; j < 6; ++j) {
                const bf16x8 b = *(const bf16x8*)bp[j];
                acc[j] = __builtin_amdgcn_mfma_f32_16x16x32_bf16(a, b, acc[j], 0, 0, 0);
                bp[j] += 32;
            }
        }
        #pragma unroll
        for (int j = 0; j < 6; ++j) {
            const int col = (6 * w + j) * 16 + r;
            const float bv = Uib[col];
            #pragma unroll
            for (int jj = 0; jj < 4; ++jj)
                iuoL[(size_t)(kg * 4 + jj) * 768 + col] = (bf16_t)(acc[j][jj] + bv);
        }
    }
    __syncthreads();

    // ---- gate phase: 512 thr x 8 (row,col) pairs ----
    {
        const int col = t & 255;
        const int rbase = t >> 8;
        for (int i = 0; i < 8; ++i) {
            const int rr = rbase + 2 * i;
            const int g = g0 + rr;
            const float Wf = (float)WxL[(size_t)rr * 1024 + col];
            const float Wi = (float)WxL[(size_t)rr * 1024 + 256 + col];
            const float Wu = (float)WxL[(size_t)rr * 1024 + 512 + col];
            const float Wo = (float)WxL[(size_t)rr * 1024 + 768 + col];
            float bfa = 0.f;
            #pragma unroll
            for (int k = 0; k < KK; ++k) {
                const int ch = childL[rr][k];
                if (ch >= 0) {
                    const int slot = rr * 8 + k;
                    const int ps = ((col >> 3) + 4 * (slot & 7)) & 31;
                    const float hf = (float)chH[(size_t)slot * 256 + ps * 8 + (col & 7)];
                    const float fk = sigmoidf_(Wf + hf);
                    bfa = fmaf(fk, cprev[(size_t)ch * HH + col], bfa);
                }
            }
            const float ig = sigmoidf_((float)iuoL[(size_t)rr * 768 + col] + Wi);
            const float ug = tanhf((float)iuoL[(size_t)rr * 768 + 256 + col] + Wu);
            const float og = sigmoidf_((float)iuoL[(size_t)rr * 768 + 512 + col] + Wo);
            const float nc = fmaf(ig, ug, bfa);
            const float nh = og * tanhf(nc);
            cnext[(size_t)g * HH + col] = nc;
            hnext[(size_t)g * HH + col] = (bf16_t)nh;
        }
    }
}

// ---------------- siamese head ----------------
__global__ __launch_bounds__(256) void k_final(
    const bf16_t* __restrict__ hlast, const bf16_t* __restrict__ xbf,
    const float* __restrict__ dW, const float* __restrict__ db,
    const float* __restrict__ oW, const float* __restrict__ ob,
    float* __restrict__ out)
{
    __shared__ __align__(16) float ad[8][HH];
    __shared__ __align__(16) float xx[8][512];
    const int t = threadIdx.x;
    const int n0 = blockIdx.x * 8;
    const size_t xoff1 = (size_t)(LL - 1) * NN * HH;
    const size_t xoff2 = (size_t)LN * HH + xoff1;
    #pragma unroll
    for (int rr = 0; rr < 8; ++rr) {
        const int n = n0 + rr;
        const float h1 = (float)hlast[(size_t)n * HH + t] + (float)xbf[xoff1 + (size_t)n * HH + t];
        const float h2 = (float)hlast[((size_t)NN + n) * HH + t] + (float)xbf[xoff2 + (size_t)n * HH + t];
        ad[rr][t] = fabsf(h1 - h2);
    }
    __syncthreads();
    float a0[8], a1[8];
    #pragma unroll
    for (int rr = 0; rr < 8; ++rr) { a0[rr] = 0.f; a1[rr] = 0.f; }
    for (int k = 0; k < HH; k += 4) {
        #pragma unroll
        for (int kk = 0; kk < 4; ++kk) {
            const float b0 = dW[(size_t)(k + kk) * 512 + t];
            const float b1 = dW[(size_t)(k + kk) * 512 + 256 + t];
            #pragma unroll
            for (int rr = 0; rr < 8; ++rr) {
                const float av = ad[rr][k + kk];
                a0[rr] = fmaf(av, b0, a0[rr]);
                a1[rr] = fmaf(av, b1, a1[rr]);
            }
        }
    }
    const float db0 = db[t], db1 = db[256 + t];
    #pragma unroll
    for (int rr = 0; rr < 8; ++rr) {
        xx[rr][t] = tanhf(a0[rr] + db0);
        xx[rr][256 + t] = tanhf(a1[rr] + db1);
    }
    __syncthreads();
    const int w = t >> 6, lane = t & 63;
    for (int rr = w; rr < 8; rr += 4) {
        float p0 = 0.f, p1 = 0.f;
        for (int k = lane; k < 512; k += 64) {
            const float xv = xx[rr][k];
            p0 = fmaf(xv, oW[2 * k + 0], p0);
            p1 = fmaf(xv, oW[2 * k + 1], p1);
        }
        #pragma unroll
        for (int off = 32; off > 0; off >>= 1) {
            p0 += __shfl_down(p0, off);
            p1 += __shfl_down(p1, off);
        }
        if (lane == 0) {
            const float l0 = p0 + ob[0], l1 = p1 + ob[1];
            const float mx = fmaxf(l0, l1);
            const float e0 = expf(l0 - mx), e1 = expf(l1 - mx);
            const float inv = 1.f / (e0 + e1);
            out[(size_t)(n0 + rr) * 2 + 0] = e0 * inv;
            out[(size_t)(n0 + rr) * 2 + 1] = e1 * inv;
        }
    }
}

extern "C" void kernel_launch(void* const* d_in, const int* in_sizes, int n_in,
                              void* d_out, int out_size, void* d_ws, size_t ws_size,
                              hipStream_t stream) {
    (void)in_sizes; (void)n_in; (void)out_size; (void)ws_size;
    const int*   tok1 = (const int*)d_in[0];
    const int*   idx1 = (const int*)d_in[1];
    const int*   tok2 = (const int*)d_in[2];
    const int*   idx2 = (const int*)d_in[3];
    const float* E    = (const float*)d_in[4];
    const float* linW = (const float*)d_in[5];
    const float* linb = (const float*)d_in[6];
    const float* UfW  = (const float*)d_in[7];
    const float* Ufb  = (const float*)d_in[8];
    const float* UiW  = (const float*)d_in[9];
    const float* Uib  = (const float*)d_in[10];
    const float* WW   = (const float*)d_in[11];
    const float* Wb   = (const float*)d_in[12];
    const float* dW   = (const float*)d_in[13];
    const float* db   = (const float*)d_in[14];
    const float* oW   = (const float*)d_in[15];
    const float* ob   = (const float*)d_in[16];
    float* out = (float*)d_out;

    // ws: xbf | UNION{ Ebf (dead after embed) | hb0 hb1 c0 c1 } | weights  (~52.3 MB)
    bf16_t* xbf = (bf16_t*)d_ws;                        // 12,582,912 elems
    bf16_t* uni = xbf + (size_t)12582912;
    bf16_t* Ebf = uni;                                  // 12,800,000 elems
    bf16_t* hb0 = uni;                                  // 1,048,576
    bf16_t* hb1 = hb0 + (size_t)1048576;                // 1,048,576
    float*  c0  = (float*)(hb1 + (size_t)1048576);      // 1,048,576 f32
    float*  c1  = c0 + (size_t)1048576;
    bf16_t* wts   = uni + (size_t)12800000;
    bf16_t* linWt = wts;                                // 262,144
    bf16_t* WWt   = linWt + (size_t)262144;             // 262,144
    bf16_t* UfWt  = WWt   + (size_t)262144;             // 65,536
    bf16_t* UiWt  = UfWt  + (size_t)65536;              // 196,608

    k_cvtE<<<2048, 256, 0, stream>>>(E, Ebf, VV * HH / 4);
    k_cvtW<<<3072, 256, 0, stream>>>(linW, WW, UfW, UiW, linWt, WWt, UfWt, UiWt);

    k_embed<<<768, 512, 0, stream>>>(tok1, tok2, Ebf, linWt, linb, xbf);

    bf16_t *hp = hb0, *hn = hb1;
    float  *cp = c0,  *cn = c1;
    for (int l = 0; l < LL; ++l) {
        // l==0: idx[0] all -1 -> no hprev/cprev reads (poison/alias safe)
        k_stepF<<<256, 512, 0, stream>>>(xbf, hp, cp, idx1, idx2, l,
                                         UfWt, Ufb, UiWt, Uib, WWt, Wb, hn, cn);
        bf16_t* th = hp; hp = hn; hn = th;
        float*  tc = cp; cp = cn; cn = tc;
    }

    k_final<<<NN / 8, 256, 0, stream>>>(hp, xbf, dW, db, oW, ob, out);
}